// Round 10
// baseline (100.925 us; speedup 1.0000x reference)
//
#include <hip/hip_runtime.h>
#include <cstdint>
#include <cstddef>

typedef __bf16 bf16;
typedef bf16 bf16x4 __attribute__((ext_vector_type(4)));
typedef bf16 bf16x8 __attribute__((ext_vector_type(8)));
typedef float f32x4 __attribute__((ext_vector_type(4)));

#define S_LEN 2048
#define DIM   1024
#define NHEAD 16
#define HDIM  64

__device__ __forceinline__ f32x4 mfma16(bf16x8 a, bf16x8 b, f32x4 c) {
    return __builtin_amdgcn_mfma_f32_16x16x32_bf16(a, b, c, 0, 0, 0);
}

__device__ __forceinline__ float exp2fast(float x) {
    return __builtin_amdgcn_exp2f(x);   // v_exp_f32: 2^x
}

__device__ __forceinline__ void gload_lds16(const bf16* g, bf16* l) {
    __builtin_amdgcn_global_load_lds(
        (const __attribute__((address_space(1))) unsigned*)g,
        (__attribute__((address_space(3))) unsigned*)l, 16, 0, 0);
}

// ---------------- convert x (fp32 -> bf16) ----------------
__global__ __launch_bounds__(256) void cvt_x_kernel(const float* __restrict__ x,
                                                    bf16* __restrict__ xb) {
    int i = blockIdx.x * 256 + threadIdx.x;
    float4 v = ((const float4*)x)[i];
    bf16x4 o = { (bf16)v.x, (bf16)v.y, (bf16)v.z, (bf16)v.w };
    ((bf16x4*)xb)[i] = o;
}

// ---------------- transpose + convert W [K,N] fp32 -> WT [N,K] bf16 ----------------
__global__ __launch_bounds__(256) void wt_kernel(const float* __restrict__ Wq, const float* __restrict__ Wk,
                                                 const float* __restrict__ Wv, const float* __restrict__ Wo,
                                                 bf16* __restrict__ WqT, bf16* __restrict__ WkT,
                                                 bf16* __restrict__ WvT, bf16* __restrict__ WoT) {
    const float* W; bf16* WT;
    int z = blockIdx.z;
    if      (z == 0) { W = Wq; WT = WqT; }
    else if (z == 1) { W = Wk; WT = WkT; }
    else if (z == 2) { W = Wv; WT = WvT; }
    else             { W = Wo; WT = WoT; }
    __shared__ bf16 tile[64][72];
    int k0 = blockIdx.x * 64, n0 = blockIdx.y * 64;
    int t = threadIdx.x;
#pragma unroll
    for (int p = 0; p < 4; ++p) {
        int task = p * 256 + t;
        int ki = task >> 4, nj = (task & 15) * 4;
        float4 v = *(const float4*)(W + (size_t)(k0 + ki) * DIM + n0 + nj);
        tile[ki][nj + 0] = (bf16)v.x; tile[ki][nj + 1] = (bf16)v.y;
        tile[ki][nj + 2] = (bf16)v.z; tile[ki][nj + 3] = (bf16)v.w;
    }
    __syncthreads();
#pragma unroll
    for (int p = 0; p < 4; ++p) {
        int task = p * 256 + t;
        int ni = task >> 4, kj = (task & 15) * 4;
        bf16x4 o = { tile[kj + 0][ni], tile[kj + 1][ni], tile[kj + 2][ni], tile[kj + 3][ni] };
        *(bf16x4*)(WT + (size_t)(n0 + ni) * DIM + k0 + kj) = o;
    }
}

// ================= fused QKV GEMM: 256x256 tile, 8 waves, BK=64, counted-vmcnt pipeline =================
// C[4096,3072] = xb @ Wall^T. LDS per slot: A[2 ks][256][32] (32KB) + B[2 ks][256][32] (32KB), 2 slots = 128KB.
// Staging unit u = k-half of a tile (A+B, 4 gload_lds/thread). Schedule per K-tile kt:
//   boundary: vmcnt(4)  -> u0(kt) landed (u1(kt) may be in flight), barrier
//   stage u0(kt+1) -> slot^1    [safe: reads are on slot]
//   phases 0,1: ds_read ks0 (u0 data), 32 MFMA
//   mid: vmcnt(4)  -> u1(kt) landed (u0(kt+1) in flight), barrier
//   stage u1(kt+1) -> slot^1
//   phases 2,3: ds_read ks1 (u1 data), 32 MFMA
// Loads never drain below 4 outstanding in the main loop (T3+T4); setprio around MFMA clusters (T5).
// XOR swizzle (row&3)<<4 applied to BOTH stage-source k-offset and ds_read offset (rule #21) -> 4-way residual.
__global__ __launch_bounds__(512, 2) void gemm_qkv_kernel(const bf16* __restrict__ xb,
                                                          const bf16* __restrict__ Wall,
                                                          const float* __restrict__ bq, const float* __restrict__ bv,
                                                          const float* __restrict__ cosp, const float* __restrict__ sinp,
                                                          bf16* __restrict__ qT, bf16* __restrict__ kT,
                                                          bf16* __restrict__ vT) {
    __shared__ bf16 lds[2][32768];            // 128 KB
    int t = threadIdx.x, lane = t & 63, w = t >> 6;
    int wr = w >> 2, wc = w & 3;              // 2(M) x 4(N) waves; per-wave 128x64 output
    int lc = lane & 15, lr = lane >> 4;
    int bid = blockIdx.x;
    int bx = bid / 12, by = bid % 12;         // 16 x 12 grid
    int m0 = bx * 256, n0 = by * 256;

    // staging source pointers (pass p in {0,1}; i = p*512+t; row = i>>2; swizzled k-offset)
    int i0 = t, i1 = 512 + t;
    int r0 = i0 >> 2, r1 = i1 >> 2;
    int ke0 = (((i0 & 3) ^ (r0 & 3)) << 3);
    int ke1 = (((i1 & 3) ^ (r1 & 3)) << 3);
    const bf16* srcA0 = xb   + (size_t)(m0 + r0) * DIM + ke0;
    const bf16* srcA1 = xb   + (size_t)(m0 + r1) * DIM + ke1;
    const bf16* srcB0 = Wall + (size_t)(n0 + r0) * DIM + ke0;
    const bf16* srcB1 = Wall + (size_t)(n0 + r1) * DIM + ke1;

#define STAGE_UNIT(kt_, u_) {                                              \
        bf16* d = (bf16*)lds[(kt_) & 1] + (u_) * 8192 + w * 512;           \
        int ko = (kt_) * 64 + (u_) * 32;                                   \
        gload_lds16(srcA0 + ko, d);                                        \
        gload_lds16(srcB0 + ko, d + 16384);                                \
        gload_lds16(srcA1 + ko, d + 4096);                                 \
        gload_lds16(srcB1 + ko, d + 4096 + 16384);                         \
    }

    f32x4 acc[8][4] = {};
    const int aoff = (lr * 16) ^ ((lc & 3) << 4);          // swizzled byte offset in 64B k-row
    const int arow = (wr * 128 + lc) * 64;                  // A base byte row offset
    const int brow = 32768 + (wc * 64 + lc) * 64;           // B region base

    const int NT = DIM / 64;                                // 16 K-tiles
    STAGE_UNIT(0, 0);
    STAGE_UNIT(0, 1);

    for (int kt = 0; kt < NT; ++kt) {
        asm volatile("s_waitcnt vmcnt(4)" ::: "memory");    // u0(kt) landed
        __builtin_amdgcn_s_barrier();
        asm volatile("" ::: "memory");
        if (kt + 1 < NT) STAGE_UNIT(kt + 1, 0);
        const char* base = (const char*)lds[kt & 1];
        bf16x8 aF[4], bF[4];
        // ---- ks = 0 (unit 0 data) ----
#pragma unroll
        for (int nf = 0; nf < 4; ++nf)
            bF[nf] = *(const bf16x8*)(base + brow + nf * 1024 + aoff);
#pragma unroll
        for (int m4 = 0; m4 < 4; ++m4)
            aF[m4] = *(const bf16x8*)(base + arow + m4 * 1024 + aoff);
        __builtin_amdgcn_s_setprio(1);
#pragma unroll
        for (int m4 = 0; m4 < 4; ++m4)
#pragma unroll
            for (int nf = 0; nf < 4; ++nf)
                acc[m4][nf] = mfma16(aF[m4], bF[nf], acc[m4][nf]);
        __builtin_amdgcn_s_setprio(0);
#pragma unroll
        for (int m4 = 0; m4 < 4; ++m4)
            aF[m4] = *(const bf16x8*)(base + arow + 4096 + m4 * 1024 + aoff);
        __builtin_amdgcn_s_setprio(1);
#pragma unroll
        for (int m4 = 0; m4 < 4; ++m4)
#pragma unroll
            for (int nf = 0; nf < 4; ++nf)
                acc[4 + m4][nf] = mfma16(aF[m4], bF[nf], acc[4 + m4][nf]);
        __builtin_amdgcn_s_setprio(0);
        // ---- mid: u1(kt) must be landed for ks=1 reads ----
        if (kt + 1 < NT) asm volatile("s_waitcnt vmcnt(4)" ::: "memory");
        else             asm volatile("s_waitcnt vmcnt(0)" ::: "memory");
        __builtin_amdgcn_s_barrier();
        asm volatile("" ::: "memory");
        if (kt + 1 < NT) STAGE_UNIT(kt + 1, 1);
        // ---- ks = 1 (unit 1 data; +16384 bytes in both regions) ----
#pragma unroll
        for (int nf = 0; nf < 4; ++nf)
            bF[nf] = *(const bf16x8*)(base + 16384 + brow + nf * 1024 + aoff);
#pragma unroll
        for (int m4 = 0; m4 < 4; ++m4)
            aF[m4] = *(const bf16x8*)(base + 16384 + arow + m4 * 1024 + aoff);
        __builtin_amdgcn_s_setprio(1);
#pragma unroll
        for (int m4 = 0; m4 < 4; ++m4)
#pragma unroll
            for (int nf = 0; nf < 4; ++nf)
                acc[m4][nf] = mfma16(aF[m4], bF[nf], acc[m4][nf]);
        __builtin_amdgcn_s_setprio(0);
#pragma unroll
        for (int m4 = 0; m4 < 4; ++m4)
            aF[m4] = *(const bf16x8*)(base + 16384 + arow + 4096 + m4 * 1024 + aoff);
        __builtin_amdgcn_s_setprio(1);
#pragma unroll
        for (int m4 = 0; m4 < 4; ++m4)
#pragma unroll
            for (int nf = 0; nf < 4; ++nf)
                acc[4 + m4][nf] = mfma16(aF[m4], bF[nf], acc[4 + m4][nf]);
        __builtin_amdgcn_s_setprio(0);
    }
#undef STAGE_UNIT

    // epilogue: by 0-3 -> Q (RoPE+bias), 4-7 -> K (RoPE), 8-11 -> V (bias, transposed write)
    int z = by >> 2;
    int h = (by & 3) * 4 + wc;
    int row0 = m0 + wr * 128 + lr * 4;
    if (z < 2) {
        bf16* qkT = (z == 0) ? qT : kT;
#pragma unroll
        for (int nf = 0; nf < 2; ++nf) {
            int hd1 = nf * 16 + lc;          // 0..31; rotate pair lives at acc[.][nf+2]
            float b1 = (z == 0) ? bq[h * HDIM + hd1] : 0.0f;
            float b2 = (z == 0) ? bq[h * HDIM + hd1 + 32] : 0.0f;
#pragma unroll
            for (int mf = 0; mf < 8; ++mf) {
#pragma unroll
                for (int r = 0; r < 4; ++r) {
                    int bs = row0 + mf * 16 + r;
                    size_t cb = (size_t)bs * HDIM + hd1;
                    float c1 = cosp[cb], s1 = sinp[cb];
                    float c2 = cosp[cb + 32], s2 = sinp[cb + 32];
                    float v1 = acc[mf][nf][r] + b1;
                    float v2 = acc[mf][nf + 2][r] + b2;
                    int b = bs >> 11, s = bs & (S_LEN - 1);
                    size_t o = ((size_t)(b * NHEAD + h) * S_LEN + s) * HDIM;
                    qkT[o + hd1]      = (bf16)(v1 * c1 - v2 * s1);
                    qkT[o + hd1 + 32] = (bf16)(v2 * c2 + v1 * s2);
                }
            }
        }
    } else {
#pragma unroll
        for (int nf = 0; nf < 4; ++nf) {
            int hd = nf * 16 + lc;
            float bvv = bv[h * HDIM + hd];
#pragma unroll
            for (int mf = 0; mf < 8; ++mf) {
                bf16x4 o;
#pragma unroll
                for (int r = 0; r < 4; ++r) o[r] = (bf16)(acc[mf][nf][r] + bvv);
                int bs = row0 + mf * 16;
                int b = bs >> 11, s = bs & (S_LEN - 1);
                *(bf16x4*)(vT + ((size_t)((b * NHEAD + h) * HDIM + hd)) * S_LEN + s) = o;
            }
        }
    }
}

// ---------------- out GEMM: 128x128 / 4-wave / ring-3 / counted vmcnt (R3 structure) ----------------
__device__ __forceinline__ void stage_tile(const bf16* __restrict__ A, const bf16* __restrict__ BT,
                                           int m0, int n0, int k0,
                                           bf16* sA, bf16* sB, int w, int lane) {
#pragma unroll
    for (int p = 0; p < 2; ++p) {
        int c = p * 256 + w * 64 + lane;
        const bf16* ga = A + (size_t)(m0 + (c >> 2)) * DIM + k0 + (c & 3) * 8;
        gload_lds16(ga, sA + (p * 256 + w * 64) * 8);
        const bf16* gb = BT + (size_t)(n0 + (c >> 2)) * DIM + k0 + (c & 3) * 8;
        gload_lds16(gb, sB + (p * 256 + w * 64) * 8);
    }
}

__global__ __launch_bounds__(256, 3) void gemm_out_kernel(const bf16* __restrict__ ctx, const bf16* __restrict__ WoT,
                                                          const float* __restrict__ bo, float* __restrict__ out) {
    __shared__ bf16 sA[3][128 * 32];
    __shared__ bf16 sB[3][128 * 32];
    int m0 = blockIdx.x * 128, n0 = blockIdx.y * 128;
    int t = threadIdx.x;
    int lane = t & 63, w = t >> 6;
    int wr = w >> 1, wc = w & 1;
    int lc = lane & 15, lr = lane >> 4;
    const int NSTEP = DIM / 32;

    f32x4 acc[4][4] = {};
    stage_tile(ctx, WoT, m0, n0, 0,  sA[0], sB[0], w, lane);
    stage_tile(ctx, WoT, m0, n0, 32, sA[1], sB[1], w, lane);

    int rs = 0, ss = 2;
    for (int kt = 0; kt < NSTEP; ++kt) {
        if (kt < NSTEP - 1) asm volatile("s_waitcnt vmcnt(4)" ::: "memory");
        else                asm volatile("s_waitcnt vmcnt(0)" ::: "memory");
        __builtin_amdgcn_s_barrier();
        asm volatile("" ::: "memory");
        if (kt < NSTEP - 2)
            stage_tile(ctx, WoT, m0, n0, (kt + 2) * 32, sA[ss], sB[ss], w, lane);

        const bf16* pa = sA[rs] + (wr * 64 + lc) * 32 + lr * 8;
        const bf16* pb = sB[rs] + (wc * 64 + lc) * 32 + lr * 8;
        bf16x8 af[4], bfr[4];
#pragma unroll
        for (int m = 0; m < 4; ++m) af[m] = *(const bf16x8*)(pa + m * 16 * 32);
#pragma unroll
        for (int n = 0; n < 4; ++n) bfr[n] = *(const bf16x8*)(pb + n * 16 * 32);
#pragma unroll
        for (int m = 0; m < 4; ++m)
#pragma unroll
            for (int n = 0; n < 4; ++n)
                acc[m][n] = mfma16(af[m], bfr[n], acc[m][n]);
        rs = (rs == 2) ? 0 : rs + 1;
        ss = (ss == 2) ? 0 : ss + 1;
    }

    int row0 = m0 + wr * 64 + lr * 4;
    int col0 = n0 + wc * 64 + lc;
#pragma unroll
    for (int nf = 0; nf < 4; ++nf) {
        int col = col0 + nf * 16;
        float bvv = bo[col];
#pragma unroll
        for (int mf = 0; mf < 4; ++mf)
#pragma unroll
            for (int r = 0; r < 4; ++r)
                out[(size_t)(row0 + mf * 16 + r) * DIM + col] = acc[mf][nf][r] + bvv;
    }
}

// ---------------- flash attention (R9: swapped QK^T, reg prefetch, XCD KV-locality swizzle) ----------------
__global__ __launch_bounds__(64) void attn_kernel(const bf16* __restrict__ qT, const bf16* __restrict__ kT,
                                                  const bf16* __restrict__ vT, bf16* __restrict__ ctx) {
    int bid = blockIdx.x + 64 * blockIdx.y;      // 2048 blocks
    int xcd = bid & 7, idx = bid >> 3;
    int bh = xcd * 4 + (idx >> 6);               // 4 heads per XCD (2MB KV < 4MB L2)
    int q0 = (idx & 63) * 32;
    int b = bh >> 4, h = bh & 15;
    int lane = threadIdx.x;
    int lc = lane & 15, lr = lane >> 4;
    __shared__ bf16 sP[32 * 64];
    char* sPb = (char*)sP;
    const bf16* Qb = qT + (size_t)bh * S_LEN * HDIM;
    const bf16* Kb = kT + (size_t)bh * S_LEN * HDIM;
    const bf16* Vb = vT + (size_t)bh * HDIM * S_LEN;

    const float SCL = 0.125f * 1.44269504089f;
    const int swz = (lc & 7) << 4;

    bf16x8 qf[2][2];
#pragma unroll
    for (int mf = 0; mf < 2; ++mf)
#pragma unroll
        for (int kk = 0; kk < 2; ++kk)
            qf[mf][kk] = *(const bf16x8*)(Qb + (size_t)(q0 + mf * 16 + lc) * HDIM + kk * 32 + lr * 8);

    f32x4 accO[2][4] = {};
    float mrun[2] = { -30000.0f, -30000.0f };
    float lrun[2] = { 0.0f, 0.0f };

    int klo = (q0 >= 256) ? ((q0 - 256) >> 6) : 0;
    int khi = (q0 + 31) >> 6;

    bf16x8 kfc[8], kfn[8], vf[8];
#pragma unroll
    for (int nf = 0; nf < 4; ++nf)
#pragma unroll
        for (int kk = 0; kk < 2; ++kk)
            kfc[nf * 2 + kk] = *(const bf16x8*)(Kb + (size_t)(klo * 64 + nf * 16 + lc) * HDIM + kk * 32 + lr * 8);

    for (int kt = klo; kt <= khi; ++kt) {
        int kbase = kt * 64;
#pragma unroll
        for (int n4 = 0; n4 < 4; ++n4)
#pragma unroll
            for (int kk = 0; kk < 2; ++kk)
                vf[n4 * 2 + kk] = *(const bf16x8*)(Vb + (size_t)(n4 * 16 + lc) * S_LEN + kbase + kk * 32 + lr * 8);
        if (kt < khi) {
#pragma unroll
            for (int nf = 0; nf < 4; ++nf)
#pragma unroll
                for (int kk = 0; kk < 2; ++kk)
                    kfn[nf * 2 + kk] = *(const bf16x8*)(Kb + (size_t)(kbase + 64 + nf * 16 + lc) * HDIM + kk * 32 + lr * 8);
        }

        f32x4 sacc[2][4] = {};
        __builtin_amdgcn_s_setprio(1);
#pragma unroll
        for (int nf = 0; nf < 4; ++nf)
#pragma unroll
            for (int kk = 0; kk < 2; ++kk) {
                sacc[0][nf] = mfma16(kfc[nf * 2 + kk], qf[0][kk], sacc[0][nf]);
                sacc[1][nf] = mfma16(kfc[nf * 2 + kk], qf[1][kk], sacc[1][nf]);
            }
        __builtin_amdgcn_s_setprio(0);
#pragma unroll
        for (int mf = 0; mf < 2; ++mf) {
            int qi = q0 + mf * 16 + lc;
#pragma unroll
            for (int nf = 0; nf < 4; ++nf)
#pragma unroll
                for (int r = 0; r < 4; ++r) {
                    int ki = kbase + nf * 16 + lr * 4 + r;
                    bool keep = (ki <= qi) && (ki >= qi - 256);
                    sacc[mf][nf][r] = keep ? sacc[mf][nf][r] * SCL : -30000.0f;
                }
        }
#pragma unroll
        for (int mf = 0; mf < 2; ++mf) {
            float mx = sacc[mf][0][0];
#pragma unroll
            for (int nf = 0; nf < 4; ++nf)
#pragma unroll
                for (int r = 0; r < 4; ++r) mx = fmaxf(mx, sacc[mf][nf][r]);
            mx = fmaxf(mx, __shfl_xor(mx, 16));
            mx = fmaxf(mx, __shfl_xor(mx, 32));
            float mnew = fmaxf(mrun[mf], mx);
            float alpha = exp2fast(mrun[mf] - mnew);
            mrun[mf] = mnew;
            float rsum = 0.0f;
#pragma unroll
            for (int nf = 0; nf < 4; ++nf)
#pragma unroll
                for (int r = 0; r < 4; ++r) {
                    float e = exp2fast(sacc[mf][nf][r] - mnew);
                    sacc[mf][nf][r] = e;
                    rsum += e;
                }
            rsum += __shfl_xor(rsum, 16);
            rsum += __shfl_xor(rsum, 32);
            lrun[mf] = lrun[mf] * alpha + rsum;
            float aq[4];
#pragma unroll
            for (int r = 0; r < 4; ++r) aq[r] = __shfl(alpha, lr * 4 + r);
#pragma unroll
            for (int n4 = 0; n4 < 4; ++n4)
#pragma unroll
                for (int r = 0; r < 4; ++r) accO[mf][n4][r] *= aq[r];
        }
#pragma unroll
        for (int mf = 0; mf < 2; ++mf)
#pragma unroll
            for (int nf = 0; nf < 4; ++nf) {
                bf16x4 o = { (bf16)sacc[mf][nf][0], (bf16)sacc[mf][nf][1],
                             (bf16)sacc[mf][nf][2], (bf16)sacc[mf][nf][3] };
                int wb = ((mf * 16 + lc) * 64 + nf * 16 + lr * 4) * 2;
                *(bf16x4*)(sPb + (wb ^ swz)) = o;
            }
        asm volatile("s_waitcnt lgkmcnt(0)" ::: "memory");
        bf16x8 pf[2][2];
#pragma unroll
        for (int mf = 0; mf < 2; ++mf)
#pragma unroll
            for (int kk = 0; kk < 2; ++kk) {
                int rb = ((mf * 16 + lc) * 64 + kk * 32 + lr * 8) * 2;
                pf[mf][kk] = *(const bf16x8*)(sPb + (rb ^ swz));
            }
        __builtin_amdgcn_s_setprio(1);
#pragma unroll
        for (int n4 = 0; n4 < 4; ++n4)
#pragma unroll
            for (int kk = 0; kk < 2; ++kk) {
                accO[0][n4] = mfma16(pf[0][kk], vf[n4 * 2 + kk], accO[0][n4]);
                accO[1][n4] = mfma16(pf[1][kk], vf[n4 * 2 + kk], accO[1][n4]);
            }
        __builtin_amdgcn_s_setprio(0);
#pragma unroll
        for (int i = 0; i < 8; ++i) kfc[i] = kfn[i];
    }
#pragma unroll
    for (int mf = 0; mf < 2; ++mf) {
        float linv = 1.0f / lrun[mf];
        float lq[4];
#pragma unroll
        for (int r = 0; r < 4; ++r) lq[r] = __shfl(linv, lr * 4 + r);
#pragma unroll
        for (int n4 = 0; n4 < 4; ++n4)
#pragma unroll
            for (int r = 0; r < 4; ++r) {
                int s = q0 + mf * 16 + lr * 4 + r;
                int d = n4 * 16 + lc;
                ctx[((size_t)(b * S_LEN + s)) * DIM + h * HDIM + d] = (bf16)(accO[mf][n4][r] * lq[r]);
            }
    }
}

extern "C" void kernel_launch(void* const* d_in, const int* in_sizes, int n_in,
                              void* d_out, int out_size, void* d_ws, size_t ws_size,
                              hipStream_t stream) {
    const float* x    = (const float*)d_in[0];
    const float* cosp = (const float*)d_in[2];
    const float* sinp = (const float*)d_in[3];
    const float* Wq   = (const float*)d_in[4];
    const float* bq   = (const float*)d_in[5];
    const float* Wk   = (const float*)d_in[6];
    const float* Wv   = (const float*)d_in[7];
    const float* bv   = (const float*)d_in[8];
    const float* Wo   = (const float*)d_in[9];
    const float* bo   = (const float*)d_in[10];
    float* out = (float*)d_out;

    char* ws = (char*)d_ws;
    const size_t MB = 1ull << 20;
    bf16* xb  = (bf16*)(ws + 0 * MB);
    bf16* WqT = (bf16*)(ws + 8 * MB);   // WqT/WkT/WvT contiguous => fused [3072][1024]
    bf16* WkT = (bf16*)(ws + 10 * MB);
    bf16* WvT = (bf16*)(ws + 12 * MB);
    bf16* WoT = (bf16*)(ws + 14 * MB);
    bf16* qT  = (bf16*)(ws + 16 * MB);
    bf16* kT  = (bf16*)(ws + 24 * MB);
    bf16* vT  = (bf16*)(ws + 32 * MB);
    bf16* ctx = (bf16*)(ws + 40 * MB);

    cvt_x_kernel<<<4096, 256, 0, stream>>>(x, xb);
    wt_kernel<<<dim3(16, 16, 4), 256, 0, stream>>>(Wq, Wk, Wv, Wo, WqT, WkT, WvT, WoT);
    gemm_qkv_kernel<<<192, 512, 0, stream>>>(xb, WqT, bq, bv, cosp, sinp, qT, kT, vT);
    attn_kernel<<<dim3(64, 32), 64, 0, stream>>>(qT, kT, vT, ctx);
    gemm_out_kernel<<<dim3(32, 8), 256, 0, stream>>>(ctx, WoT, bo, out);
}

// Round 11
// 95.445 us; speedup vs baseline: 1.0574x; 1.0574x over previous
//
#include <hip/hip_runtime.h>
#include <cstdint>
#include <cstddef>

typedef __bf16 bf16;
typedef bf16 bf16x4 __attribute__((ext_vector_type(4)));
typedef bf16 bf16x8 __attribute__((ext_vector_type(8)));
typedef float f32x4 __attribute__((ext_vector_type(4)));

#define S_LEN 2048
#define DIM   1024
#define NHEAD 16
#define HDIM  64

__device__ __forceinline__ f32x4 mfma16(bf16x8 a, bf16x8 b, f32x4 c) {
    return __builtin_amdgcn_mfma_f32_16x16x32_bf16(a, b, c, 0, 0, 0);
}

__device__ __forceinline__ float exp2fast(float x) {
    return __builtin_amdgcn_exp2f(x);   // v_exp_f32: 2^x
}

__device__ __forceinline__ void gload_lds16(const bf16* g, bf16* l) {
    __builtin_amdgcn_global_load_lds(
        (const __attribute__((address_space(1))) unsigned*)g,
        (__attribute__((address_space(3))) unsigned*)l, 16, 0, 0);
}

// ---------------- convert x (fp32 -> bf16) ----------------
__global__ __launch_bounds__(256) void cvt_x_kernel(const float* __restrict__ x,
                                                    bf16* __restrict__ xb) {
    int i = blockIdx.x * 256 + threadIdx.x;
    float4 v = ((const float4*)x)[i];
    bf16x4 o = { (bf16)v.x, (bf16)v.y, (bf16)v.z, (bf16)v.w };
    ((bf16x4*)xb)[i] = o;
}

// ---------------- transpose + convert W [K,N] fp32 -> WT [N,K] bf16 ----------------
__global__ __launch_bounds__(256) void wt_kernel(const float* __restrict__ Wq, const float* __restrict__ Wk,
                                                 const float* __restrict__ Wv, const float* __restrict__ Wo,
                                                 bf16* __restrict__ WqT, bf16* __restrict__ WkT,
                                                 bf16* __restrict__ WvT, bf16* __restrict__ WoT) {
    const float* W; bf16* WT;
    int z = blockIdx.z;
    if      (z == 0) { W = Wq; WT = WqT; }
    else if (z == 1) { W = Wk; WT = WkT; }
    else if (z == 2) { W = Wv; WT = WvT; }
    else             { W = Wo; WT = WoT; }
    __shared__ bf16 tile[64][72];
    int k0 = blockIdx.x * 64, n0 = blockIdx.y * 64;
    int t = threadIdx.x;
#pragma unroll
    for (int p = 0; p < 4; ++p) {
        int task = p * 256 + t;
        int ki = task >> 4, nj = (task & 15) * 4;
        float4 v = *(const float4*)(W + (size_t)(k0 + ki) * DIM + n0 + nj);
        tile[ki][nj + 0] = (bf16)v.x; tile[ki][nj + 1] = (bf16)v.y;
        tile[ki][nj + 2] = (bf16)v.z; tile[ki][nj + 3] = (bf16)v.w;
    }
    __syncthreads();
#pragma unroll
    for (int p = 0; p < 4; ++p) {
        int task = p * 256 + t;
        int ni = task >> 4, kj = (task & 15) * 4;
        bf16x4 o = { tile[kj + 0][ni], tile[kj + 1][ni], tile[kj + 2][ni], tile[kj + 3][ni] };
        *(bf16x4*)(WT + (size_t)(n0 + ni) * DIM + k0 + kj) = o;
    }
}

// ---------------- 128x128 GEMM main loop, ring-3, counted vmcnt (R3-measured 42.5us) ----------------
__device__ __forceinline__ void stage_tile(const bf16* __restrict__ A, const bf16* __restrict__ BT,
                                           int m0, int n0, int k0,
                                           bf16* sA, bf16* sB, int w, int lane) {
#pragma unroll
    for (int p = 0; p < 2; ++p) {
        int c = p * 256 + w * 64 + lane;
        const bf16* ga = A + (size_t)(m0 + (c >> 2)) * DIM + k0 + (c & 3) * 8;
        gload_lds16(ga, sA + (p * 256 + w * 64) * 8);
        const bf16* gb = BT + (size_t)(n0 + (c >> 2)) * DIM + k0 + (c & 3) * 8;
        gload_lds16(gb, sB + (p * 256 + w * 64) * 8);
    }
}

__device__ __forceinline__ void gemm_main(const bf16* __restrict__ A, const bf16* __restrict__ BT,
                                          int m0, int n0, f32x4 acc[4][4]) {
    __shared__ bf16 sA[3][128 * 32];
    __shared__ bf16 sB[3][128 * 32];
    int t = threadIdx.x;
    int lane = t & 63, w = t >> 6;
    int wr = w >> 1, wc = w & 1;
    int lc = lane & 15, lr = lane >> 4;
    const int NSTEP = DIM / 32;           // 32

    stage_tile(A, BT, m0, n0, 0,  sA[0], sB[0], w, lane);
    stage_tile(A, BT, m0, n0, 32, sA[1], sB[1], w, lane);

    int rs = 0, ss = 2;
    for (int kt = 0; kt < NSTEP; ++kt) {
        if (kt < NSTEP - 1) asm volatile("s_waitcnt vmcnt(4)" ::: "memory");
        else                asm volatile("s_waitcnt vmcnt(0)" ::: "memory");
        __builtin_amdgcn_s_barrier();
        asm volatile("" ::: "memory");
        if (kt < NSTEP - 2)
            stage_tile(A, BT, m0, n0, (kt + 2) * 32, sA[ss], sB[ss], w, lane);

        const bf16* pa = sA[rs] + (wr * 64 + lc) * 32 + lr * 8;
        const bf16* pb = sB[rs] + (wc * 64 + lc) * 32 + lr * 8;
        bf16x8 af[4], bfr[4];
#pragma unroll
        for (int m = 0; m < 4; ++m) af[m] = *(const bf16x8*)(pa + m * 16 * 32);
#pragma unroll
        for (int n = 0; n < 4; ++n) bfr[n] = *(const bf16x8*)(pb + n * 16 * 32);
#pragma unroll
        for (int m = 0; m < 4; ++m)
#pragma unroll
            for (int n = 0; n < 4; ++n)
                acc[m][n] = mfma16(af[m], bfr[n], acc[m][n]);
        rs = (rs == 2) ? 0 : rs + 1;
        ss = (ss == 2) ? 0 : ss + 1;
    }
}

// ---------------- fused QKV GEMM + bias + RoPE + head relayout (R3 exact) ----------------
__global__ __launch_bounds__(256, 3) void gemm_qkv_kernel(const bf16* __restrict__ xb,
                                                          const bf16* __restrict__ WqT, const bf16* __restrict__ WkT,
                                                          const bf16* __restrict__ WvT,
                                                          const float* __restrict__ bq, const float* __restrict__ bv,
                                                          const float* __restrict__ cosp, const float* __restrict__ sinp,
                                                          bf16* __restrict__ qT, bf16* __restrict__ kT,
                                                          bf16* __restrict__ vT) {
    int z = blockIdx.z;
    const bf16* BT = (z == 0) ? WqT : (z == 1) ? WkT : WvT;
    int m0 = blockIdx.x * 128, n0 = blockIdx.y * 128;
    f32x4 acc[4][4] = {};
    gemm_main(xb, BT, m0, n0, acc);

    int t = threadIdx.x;
    int lane = t & 63, w = t >> 6;
    int wr = w >> 1, wc = w & 1;
    int lc = lane & 15, lr = lane >> 4;
    int row0 = m0 + wr * 64 + lr * 4;       // bs base
    int h = (n0 >> 6) + wc;                  // head

    if (z < 2) {
        bf16* qkT = (z == 0) ? qT : kT;
#pragma unroll
        for (int nf = 0; nf < 2; ++nf) {
            int hd1 = lc + nf * 16;          // 0..31
            int c1i = h * HDIM + hd1;
            float b1 = (z == 0) ? bq[c1i] : 0.0f;
            float b2 = (z == 0) ? bq[c1i + 32] : 0.0f;
#pragma unroll
            for (int mf = 0; mf < 4; ++mf) {
#pragma unroll
                for (int r = 0; r < 4; ++r) {
                    int bs = row0 + mf * 16 + r;
                    size_t cb = (size_t)bs * HDIM + hd1;
                    float c1 = cosp[cb], s1 = sinp[cb];
                    float c2 = cosp[cb + 32], s2 = sinp[cb + 32];
                    float v1 = acc[mf][nf][r] + b1;
                    float v2 = acc[mf][nf + 2][r] + b2;
                    int b = bs >> 11, s = bs & (S_LEN - 1);
                    size_t o = ((size_t)(b * NHEAD + h) * S_LEN + s) * HDIM;
                    qkT[o + hd1]      = (bf16)(v1 * c1 - v2 * s1);
                    qkT[o + hd1 + 32] = (bf16)(v2 * c2 + v1 * s2);
                }
            }
        }
    } else {
#pragma unroll
        for (int nf = 0; nf < 4; ++nf) {
            int hd = lc + nf * 16;
            float bvv = bv[h * HDIM + hd];
#pragma unroll
            for (int mf = 0; mf < 4; ++mf) {
                bf16x4 o;
#pragma unroll
                for (int r = 0; r < 4; ++r) o[r] = (bf16)(acc[mf][nf][r] + bvv);
                int bs = row0 + mf * 16;
                int b = bs >> 11, s = bs & (S_LEN - 1);
                *(bf16x4*)(vT + ((size_t)((b * NHEAD + h) * HDIM + hd)) * S_LEN + s) = o;
            }
        }
    }
}

__global__ __launch_bounds__(256, 3) void gemm_out_kernel(const bf16* __restrict__ ctx, const bf16* __restrict__ WoT,
                                                          const float* __restrict__ bo, float* __restrict__ out) {
    int m0 = blockIdx.x * 128, n0 = blockIdx.y * 128;
    f32x4 acc[4][4] = {};
    gemm_main(ctx, WoT, m0, n0, acc);
    int t = threadIdx.x;
    int lane = t & 63, w = t >> 6;
    int wr = w >> 1, wc = w & 1;
    int lc = lane & 15, lr = lane >> 4;
    int row0 = m0 + wr * 64 + lr * 4;
    int col0 = n0 + wc * 64 + lc;
#pragma unroll
    for (int nf = 0; nf < 4; ++nf) {
        int col = col0 + nf * 16;
        float bvv = bo[col];
#pragma unroll
        for (int mf = 0; mf < 4; ++mf)
#pragma unroll
            for (int r = 0; r < 4; ++r)
                out[(size_t)(row0 + mf * 16 + r) * DIM + col] = acc[mf][nf][r] + bvv;
    }
}

// ================ flash attention: 4-wave blocks, LDS-staged shared K/V, window 256 ================
// Block = 256 threads = 4 waves, one (b,h), 128 q-rows (wave w owns rows qb*128+w*32..+31).
// K/V tiles (64 keys) staged ONCE per block into LDS ring-2 via global_load_lds (counted vmcnt(4),
// prefetch distance 2, stage-after-consume barrier) and shared by all 4 waves: 4x fewer VMEM ops
// than the old per-wave register prefetch, and ~96 fewer VGPR -> 3 waves/SIMD.
// LDS layout: sK[slot][key][d], sV[slot][d][key], both row-stride 128B, XOR-swizzled by (row&7)<<4
// applied to BOTH the stage global-source column and the ds_read offset (involution, rule #21):
// fragment reads then spread over all 32 banks (floor-optimal).
// Per-wave math identical to R6 (swapped QK^T, lane-local softmax). Waves outside a tile's window
// skip compute but ALWAYS hit both barriers (no divergent barriers).
__global__ __launch_bounds__(256, 3) void attn_kernel(const bf16* __restrict__ qT, const bf16* __restrict__ kT,
                                                      const bf16* __restrict__ vT, bf16* __restrict__ ctx) {
    int bid = blockIdx.x + 16 * blockIdx.y;      // 512 blocks
    int xcd = bid & 7, idx = bid >> 3;           // XCD-bijective: 8 x 4bh x 16qb
    int bh = xcd * 4 + (idx >> 4);               // 4 heads per XCD (2MB KV < 4MB L2)
    int qb = idx & 15;
    int b = bh >> 4, h = bh & 15;
    int t = threadIdx.x, lane = t & 63, w = t >> 6;
    int lc = lane & 15, lr = lane >> 4;

    __shared__ bf16 sK[2][4096];                 // [slot][key(64)][d(64)] swizzled, 8KB each
    __shared__ bf16 sV[2][4096];                 // [slot][d(64)][key(64)] swizzled
    __shared__ bf16 sP[4][2048];                 // per-wave P buffer [q(32)][key(64)]

    const bf16* Qb = qT + (size_t)bh * S_LEN * HDIM;
    const bf16* Kb = kT + (size_t)bh * S_LEN * HDIM;
    const bf16* Vb = vT + (size_t)bh * HDIM * S_LEN;

    const float SCL = 0.125f * 1.44269504089f;   // 1/sqrt(64) * log2(e)
    const int swz = (lc & 7) << 4;               // involution swizzle (bytes)
    char* sPw = (char*)sP[w];

    int q0 = qb * 128 + w * 32;
    int kt_lo_b = (qb >= 2) ? (qb * 128 - 256) >> 6 : 0;
    int kt_hi_b = (qb * 128 + 127) >> 6;
    int klo_w = (q0 >= 256) ? (q0 - 256) >> 6 : 0;
    int khi_w = (q0 + 31) >> 6;

    // hoisted Q fragments
    bf16x8 qf[2][2];
#pragma unroll
    for (int mf = 0; mf < 2; ++mf)
#pragma unroll
        for (int kk = 0; kk < 2; ++kk)
            qf[mf][kk] = *(const bf16x8*)(Qb + (size_t)(q0 + mf * 16 + lc) * HDIM + kk * 32 + lr * 8);

    f32x4 accO[2][4] = {};
    float mrun[2] = { -30000.0f, -30000.0f };
    float lrun[2] = { 0.0f, 0.0f };

    // staging: tile kt -> slot s. 2 passes x (K + V) = 4 gload_lds per thread.
    // c = p*256 + t: row = c>>3 (key for K, d for V), chunk = c&7 (16B units in the 128B row).
    // source column byte pre-swizzled by (row&7)<<4; LDS dest linear (wave-uniform base, HW adds lane*16).
#define STAGE_KV(kt_, s_) {                                                             \
        int kbase_ = (kt_) * 64;                                                        \
        _Pragma("unroll")                                                               \
        for (int p = 0; p < 2; ++p) {                                                   \
            int c = p * 256 + t;                                                        \
            int row = c >> 3, ch = c & 7;                                               \
            int colb = (ch * 16) ^ ((row & 7) << 4);                                    \
            bf16* dst = (bf16*)&sK[s_][0] + (p * 256 + (t & ~63)) * 8;                  \
            gload_lds16(Kb + (size_t)(kbase_ + row) * HDIM + (colb >> 1), dst);         \
            bf16* dsv = (bf16*)&sV[s_][0] + (p * 256 + (t & ~63)) * 8;                  \
            gload_lds16(Vb + (size_t)row * S_LEN + kbase_ + (colb >> 1), dsv);          \
        }                                                                               \
    }

    STAGE_KV(kt_lo_b, 0);
    if (kt_lo_b + 1 <= kt_hi_b) STAGE_KV(kt_lo_b + 1, 1);

    for (int kt = kt_lo_b; kt <= kt_hi_b; ++kt) {
        int s = (kt - kt_lo_b) & 1;
        if (kt < kt_hi_b) asm volatile("s_waitcnt vmcnt(4)" ::: "memory");
        else              asm volatile("s_waitcnt vmcnt(0)" ::: "memory");
        __builtin_amdgcn_s_barrier();           // tile kt landed for all waves
        asm volatile("" ::: "memory");

        if (kt >= klo_w && kt <= khi_w) {
            int kbase = kt * 64;
            const char* kb = (const char*)&sK[s][0];
            const char* vb = (const char*)&sV[s][0];

            f32x4 sacc[2][4] = {};
            __builtin_amdgcn_s_setprio(1);
#pragma unroll
            for (int nf = 0; nf < 4; ++nf) {
                int key = nf * 16 + lc;
#pragma unroll
                for (int kk = 0; kk < 2; ++kk) {
                    bf16x8 kf = *(const bf16x8*)(kb + key * 128 + ((kk * 64 + lr * 16) ^ swz));
                    sacc[0][nf] = mfma16(kf, qf[0][kk], sacc[0][nf]);
                    sacc[1][nf] = mfma16(kf, qf[1][kk], sacc[1][nf]);
                }
            }
            __builtin_amdgcn_s_setprio(0);
            // mask + scale (log2 domain): lane holds (query = q0+mf*16+lc, key = kbase+nf*16+lr*4+r)
#pragma unroll
            for (int mf = 0; mf < 2; ++mf) {
                int qi = q0 + mf * 16 + lc;
#pragma unroll
                for (int nf = 0; nf < 4; ++nf)
#pragma unroll
                    for (int r = 0; r < 4; ++r) {
                        int ki = kbase + nf * 16 + lr * 4 + r;
                        bool keep = (ki <= qi) && (ki >= qi - 256);
                        sacc[mf][nf][r] = keep ? sacc[mf][nf][r] * SCL : -30000.0f;
                    }
            }
            // online softmax per query-lane
#pragma unroll
            for (int mf = 0; mf < 2; ++mf) {
                float mx = sacc[mf][0][0];
#pragma unroll
                for (int nf = 0; nf < 4; ++nf)
#pragma unroll
                    for (int r = 0; r < 4; ++r) mx = fmaxf(mx, sacc[mf][nf][r]);
                mx = fmaxf(mx, __shfl_xor(mx, 16));
                mx = fmaxf(mx, __shfl_xor(mx, 32));
                float mnew = fmaxf(mrun[mf], mx);
                float alpha = exp2fast(mrun[mf] - mnew);
                mrun[mf] = mnew;
                float rsum = 0.0f;
#pragma unroll
                for (int nf = 0; nf < 4; ++nf)
#pragma unroll
                    for (int r = 0; r < 4; ++r) {
                        float e = exp2fast(sacc[mf][nf][r] - mnew);
                        sacc[mf][nf][r] = e;
                        rsum += e;
                    }
                rsum += __shfl_xor(rsum, 16);
                rsum += __shfl_xor(rsum, 32);
                lrun[mf] = lrun[mf] * alpha + rsum;
                float aq[4];
#pragma unroll
                for (int r = 0; r < 4; ++r) aq[r] = __shfl(alpha, lr * 4 + r);
#pragma unroll
                for (int n4 = 0; n4 < 4; ++n4)
#pragma unroll
                    for (int r = 0; r < 4; ++r) accO[mf][n4][r] *= aq[r];
            }
            // P -> per-wave LDS (swizzled), then read back as PV A-fragments
#pragma unroll
            for (int mf = 0; mf < 2; ++mf)
#pragma unroll
                for (int nf = 0; nf < 4; ++nf) {
                    bf16x4 o = { (bf16)sacc[mf][nf][0], (bf16)sacc[mf][nf][1],
                                 (bf16)sacc[mf][nf][2], (bf16)sacc[mf][nf][3] };
                    int wb = ((mf * 16 + lc) * 64 + nf * 16 + lr * 4) * 2;
                    *(bf16x4*)(sPw + (wb ^ swz)) = o;
                }
            asm volatile("s_waitcnt lgkmcnt(0)" ::: "memory");
            bf16x8 pf[2][2];
#pragma unroll
            for (int mf = 0; mf < 2; ++mf)
#pragma unroll
                for (int kk = 0; kk < 2; ++kk) {
                    int rb = ((mf * 16 + lc) * 64 + kk * 32 + lr * 8) * 2;
                    pf[mf][kk] = *(const bf16x8*)(sPw + (rb ^ swz));
                }
            __builtin_amdgcn_s_setprio(1);
#pragma unroll
            for (int n4 = 0; n4 < 4; ++n4) {
                int d = n4 * 16 + lc;
#pragma unroll
                for (int kk = 0; kk < 2; ++kk) {
                    bf16x8 vf = *(const bf16x8*)(vb + d * 128 + ((kk * 64 + lr * 16) ^ swz));
                    accO[0][n4] = mfma16(pf[0][kk], vf, accO[0][n4]);
                    accO[1][n4] = mfma16(pf[1][kk], vf, accO[1][n4]);
                }
            }
            __builtin_amdgcn_s_setprio(0);
        }

        __builtin_amdgcn_s_barrier();           // all waves done reading slot s
        asm volatile("" ::: "memory");
        if (kt + 2 <= kt_hi_b) STAGE_KV(kt + 2, s);   // reuse slot s for tile kt+2
    }
#undef STAGE_KV

    // epilogue
#pragma unroll
    for (int mf = 0; mf < 2; ++mf) {
        float linv = 1.0f / lrun[mf];
        float lq[4];
#pragma unroll
        for (int r = 0; r < 4; ++r) lq[r] = __shfl(linv, lr * 4 + r);
#pragma unroll
        for (int n4 = 0; n4 < 4; ++n4)
#pragma unroll
            for (int r = 0; r < 4; ++r) {
                int s = q0 + mf * 16 + lr * 4 + r;
                int d = n4 * 16 + lc;
                ctx[((size_t)(b * S_LEN + s)) * DIM + h * HDIM + d] = (bf16)(accO[mf][n4][r] * lq[r]);
            }
    }
}

extern "C" void kernel_launch(void* const* d_in, const int* in_sizes, int n_in,
                              void* d_out, int out_size, void* d_ws, size_t ws_size,
                              hipStream_t stream) {
    const float* x    = (const float*)d_in[0];
    const float* cosp = (const float*)d_in[2];
    const float* sinp = (const float*)d_in[3];
    const float* Wq   = (const float*)d_in[4];
    const float* bq   = (const float*)d_in[5];
    const float* Wk   = (const float*)d_in[6];
    const float* Wv   = (const float*)d_in[7];
    const float* bv   = (const float*)d_in[8];
    const float* Wo   = (const float*)d_in[9];
    const float* bo   = (const float*)d_in[10];
    float* out = (float*)d_out;

    char* ws = (char*)d_ws;
    const size_t MB = 1ull << 20;
    bf16* xb  = (bf16*)(ws + 0 * MB);
    bf16* WqT = (bf16*)(ws + 8 * MB);
    bf16* WkT = (bf16*)(ws + 10 * MB);
    bf16* WvT = (bf16*)(ws + 12 * MB);
    bf16* WoT = (bf16*)(ws + 14 * MB);
    bf16* qT  = (bf16*)(ws + 16 * MB);
    bf16* kT  = (bf16*)(ws + 24 * MB);
    bf16* vT  = (bf16*)(ws + 32 * MB);
    bf16* ctx = (bf16*)(ws + 40 * MB);

    cvt_x_kernel<<<4096, 256, 0, stream>>>(x, xb);
    wt_kernel<<<dim3(16, 16, 4), 256, 0, stream>>>(Wq, Wk, Wv, Wo, WqT, WkT, WvT, WoT);
    gemm_qkv_kernel<<<dim3(32, 8, 3), 256, 0, stream>>>(xb, WqT, WkT, WvT, bq, bv, cosp, sinp, qT, kT, vT);
    attn_kernel<<<dim3(16, 32), 256, 0, stream>>>(qT, kT, vT, ctx);
    gemm_out_kernel<<<dim3(32, 8), 256, 0, stream>>>(ctx, WoT, bo, out);
}

// Round 12
// 93.126 us; speedup vs baseline: 1.0837x; 1.0249x over previous
//
#include <hip/hip_runtime.h>
#include <cstdint>
#include <cstddef>

typedef __bf16 bf16;
typedef bf16 bf16x4 __attribute__((ext_vector_type(4)));
typedef bf16 bf16x8 __attribute__((ext_vector_type(8)));
typedef float f32x4 __attribute__((ext_vector_type(4)));

#define S_LEN 2048
#define DIM   1024
#define NHEAD 16
#define HDIM  64

__device__ __forceinline__ f32x4 mfma16(bf16x8 a, bf16x8 b, f32x4 c) {
    return __builtin_amdgcn_mfma_f32_16x16x32_bf16(a, b, c, 0, 0, 0);
}

__device__ __forceinline__ float exp2fast(float x) {
    return __builtin_amdgcn_exp2f(x);   // v_exp_f32: 2^x
}

__device__ __forceinline__ void gload_lds16(const bf16* g, bf16* l) {
    __builtin_amdgcn_global_load_lds(
        (const __attribute__((address_space(1))) unsigned*)g,
        (__attribute__((address_space(3))) unsigned*)l, 16, 0, 0);
}

// ---------------- convert x (fp32 -> bf16) ----------------
__global__ __launch_bounds__(256) void cvt_x_kernel(const float* __restrict__ x,
                                                    bf16* __restrict__ xb) {
    int i = blockIdx.x * 256 + threadIdx.x;
    float4 v = ((const float4*)x)[i];
    bf16x4 o = { (bf16)v.x, (bf16)v.y, (bf16)v.z, (bf16)v.w };
    ((bf16x4*)xb)[i] = o;
}

// ---------------- transpose + convert W [K,N] fp32 -> WT [N,K] bf16 ----------------
__global__ __launch_bounds__(256) void wt_kernel(const float* __restrict__ Wq, const float* __restrict__ Wk,
                                                 const float* __restrict__ Wv, const float* __restrict__ Wo,
                                                 bf16* __restrict__ WqT, bf16* __restrict__ WkT,
                                                 bf16* __restrict__ WvT, bf16* __restrict__ WoT) {
    const float* W; bf16* WT;
    int z = blockIdx.z;
    if      (z == 0) { W = Wq; WT = WqT; }
    else if (z == 1) { W = Wk; WT = WkT; }
    else if (z == 2) { W = Wv; WT = WvT; }
    else             { W = Wo; WT = WoT; }
    __shared__ bf16 tile[64][72];
    int k0 = blockIdx.x * 64, n0 = blockIdx.y * 64;
    int t = threadIdx.x;
#pragma unroll
    for (int p = 0; p < 4; ++p) {
        int task = p * 256 + t;
        int ki = task >> 4, nj = (task & 15) * 4;
        float4 v = *(const float4*)(W + (size_t)(k0 + ki) * DIM + n0 + nj);
        tile[ki][nj + 0] = (bf16)v.x; tile[ki][nj + 1] = (bf16)v.y;
        tile[ki][nj + 2] = (bf16)v.z; tile[ki][nj + 3] = (bf16)v.w;
    }
    __syncthreads();
#pragma unroll
    for (int p = 0; p < 4; ++p) {
        int task = p * 256 + t;
        int ni = task >> 4, kj = (task & 15) * 4;
        bf16x4 o = { tile[kj + 0][ni], tile[kj + 1][ni], tile[kj + 2][ni], tile[kj + 3][ni] };
        *(bf16x4*)(WT + (size_t)(n0 + ni) * DIM + k0 + kj) = o;
    }
}

// ---------------- 128x128 GEMM main loop, ring-3, counted vmcnt (R3-measured 42.5us) ----------------
__device__ __forceinline__ void stage_tile(const bf16* __restrict__ A, const bf16* __restrict__ BT,
                                           int m0, int n0, int k0,
                                           bf16* sA, bf16* sB, int w, int lane) {
#pragma unroll
    for (int p = 0; p < 2; ++p) {
        int c = p * 256 + w * 64 + lane;
        const bf16* ga = A + (size_t)(m0 + (c >> 2)) * DIM + k0 + (c & 3) * 8;
        gload_lds16(ga, sA + (p * 256 + w * 64) * 8);
        const bf16* gb = BT + (size_t)(n0 + (c >> 2)) * DIM + k0 + (c & 3) * 8;
        gload_lds16(gb, sB + (p * 256 + w * 64) * 8);
    }
}

__device__ __forceinline__ void gemm_main(const bf16* __restrict__ A, const bf16* __restrict__ BT,
                                          int m0, int n0, f32x4 acc[4][4]) {
    __shared__ bf16 sA[3][128 * 32];
    __shared__ bf16 sB[3][128 * 32];
    int t = threadIdx.x;
    int lane = t & 63, w = t >> 6;
    int wr = w >> 1, wc = w & 1;
    int lc = lane & 15, lr = lane >> 4;
    const int NSTEP = DIM / 32;           // 32

    stage_tile(A, BT, m0, n0, 0,  sA[0], sB[0], w, lane);
    stage_tile(A, BT, m0, n0, 32, sA[1], sB[1], w, lane);

    int rs = 0, ss = 2;
    for (int kt = 0; kt < NSTEP; ++kt) {
        if (kt < NSTEP - 1) asm volatile("s_waitcnt vmcnt(4)" ::: "memory");
        else                asm volatile("s_waitcnt vmcnt(0)" ::: "memory");
        __builtin_amdgcn_s_barrier();
        asm volatile("" ::: "memory");
        if (kt < NSTEP - 2)
            stage_tile(A, BT, m0, n0, (kt + 2) * 32, sA[ss], sB[ss], w, lane);

        const bf16* pa = sA[rs] + (wr * 64 + lc) * 32 + lr * 8;
        const bf16* pb = sB[rs] + (wc * 64 + lc) * 32 + lr * 8;
        bf16x8 af[4], bfr[4];
#pragma unroll
        for (int m = 0; m < 4; ++m) af[m] = *(const bf16x8*)(pa + m * 16 * 32);
#pragma unroll
        for (int n = 0; n < 4; ++n) bfr[n] = *(const bf16x8*)(pb + n * 16 * 32);
#pragma unroll
        for (int m = 0; m < 4; ++m)
#pragma unroll
            for (int n = 0; n < 4; ++n)
                acc[m][n] = mfma16(af[m], bfr[n], acc[m][n]);
        rs = (rs == 2) ? 0 : rs + 1;
        ss = (ss == 2) ? 0 : ss + 1;
    }
}

// ---------------- fused QKV GEMM + bias + RoPE + head relayout (R3 exact) ----------------
__global__ __launch_bounds__(256, 3) void gemm_qkv_kernel(const bf16* __restrict__ xb,
                                                          const bf16* __restrict__ WqT, const bf16* __restrict__ WkT,
                                                          const bf16* __restrict__ WvT,
                                                          const float* __restrict__ bq, const float* __restrict__ bv,
                                                          const float* __restrict__ cosp, const float* __restrict__ sinp,
                                                          bf16* __restrict__ qT, bf16* __restrict__ kT,
                                                          bf16* __restrict__ vT) {
    int z = blockIdx.z;
    const bf16* BT = (z == 0) ? WqT : (z == 1) ? WkT : WvT;
    int m0 = blockIdx.x * 128, n0 = blockIdx.y * 128;
    f32x4 acc[4][4] = {};
    gemm_main(xb, BT, m0, n0, acc);

    int t = threadIdx.x;
    int lane = t & 63, w = t >> 6;
    int wr = w >> 1, wc = w & 1;
    int lc = lane & 15, lr = lane >> 4;
    int row0 = m0 + wr * 64 + lr * 4;       // bs base
    int h = (n0 >> 6) + wc;                  // head

    if (z < 2) {
        bf16* qkT = (z == 0) ? qT : kT;
#pragma unroll
        for (int nf = 0; nf < 2; ++nf) {
            int hd1 = lc + nf * 16;          // 0..31
            int c1i = h * HDIM + hd1;
            float b1 = (z == 0) ? bq[c1i] : 0.0f;
            float b2 = (z == 0) ? bq[c1i + 32] : 0.0f;
#pragma unroll
            for (int mf = 0; mf < 4; ++mf) {
#pragma unroll
                for (int r = 0; r < 4; ++r) {
                    int bs = row0 + mf * 16 + r;
                    size_t cb = (size_t)bs * HDIM + hd1;
                    float c1 = cosp[cb], s1 = sinp[cb];
                    float c2 = cosp[cb + 32], s2 = sinp[cb + 32];
                    float v1 = acc[mf][nf][r] + b1;
                    float v2 = acc[mf][nf + 2][r] + b2;
                    int b = bs >> 11, s = bs & (S_LEN - 1);
                    size_t o = ((size_t)(b * NHEAD + h) * S_LEN + s) * HDIM;
                    qkT[o + hd1]      = (bf16)(v1 * c1 - v2 * s1);
                    qkT[o + hd1 + 32] = (bf16)(v2 * c2 + v1 * s2);
                }
            }
        }
    } else {
#pragma unroll
        for (int nf = 0; nf < 4; ++nf) {
            int hd = lc + nf * 16;
            float bvv = bv[h * HDIM + hd];
#pragma unroll
            for (int mf = 0; mf < 4; ++mf) {
                bf16x4 o;
#pragma unroll
                for (int r = 0; r < 4; ++r) o[r] = (bf16)(acc[mf][nf][r] + bvv);
                int bs = row0 + mf * 16;
                int b = bs >> 11, s = bs & (S_LEN - 1);
                *(bf16x4*)(vT + ((size_t)((b * NHEAD + h) * HDIM + hd)) * S_LEN + s) = o;
            }
        }
    }
}

// ---------------- out GEMM: 128x64 tile, 2-wave blocks, ring-3, vmcnt(6) ----------------
// ISOLATED CHANGE this round: grid 32x16 = 512 blocks = 2/CU (was 256 = 1/CU -> every
// barrier+drain pair fully exposed, no inter-block TLP). LDS 3x(8KB A + 4KB B) = 36KB
// -> 4 blocks/CU capacity; 2 resident blocks' independent barriers hide each other's drains.
__device__ __forceinline__ void stage_out(const bf16* __restrict__ A, const bf16* __restrict__ BT,
                                          int m0, int n0, int k0,
                                          bf16* sA, bf16* sB, int w, int t) {
#pragma unroll
    for (int i = 0; i < 4; ++i) {
        int c = i * 128 + t;
        const bf16* ga = A + (size_t)(m0 + (c >> 2)) * DIM + k0 + (c & 3) * 8;
        gload_lds16(ga, sA + (i * 128 + w * 64) * 8);
    }
#pragma unroll
    for (int i = 0; i < 2; ++i) {
        int c = i * 128 + t;
        const bf16* gb = BT + (size_t)(n0 + (c >> 2)) * DIM + k0 + (c & 3) * 8;
        gload_lds16(gb, sB + (i * 128 + w * 64) * 8);
    }
}

__global__ __launch_bounds__(128, 2) void gemm_out_kernel(const bf16* __restrict__ ctx, const bf16* __restrict__ WoT,
                                                          const float* __restrict__ bo, float* __restrict__ out) {
    __shared__ bf16 sA[3][128 * 32];
    __shared__ bf16 sB[3][64 * 32];
    int bid = blockIdx.x + 32 * blockIdx.y;          // 512 blocks
    int wg  = (bid & 7) * 64 + (bid >> 3);           // XCD-bijective (512 % 8 == 0)
    int bx = wg & 31, by = wg >> 5;
    int m0 = bx * 128, n0 = by * 64;
    int t = threadIdx.x;
    int lane = t & 63, w = t >> 6;                   // 2 waves
    int lc = lane & 15, lr = lane >> 4;
    const int NSTEP = DIM / 32;

    f32x4 acc[4][4] = {};
    stage_out(ctx, WoT, m0, n0, 0,  sA[0], sB[0], w, t);
    stage_out(ctx, WoT, m0, n0, 32, sA[1], sB[1], w, t);

    int rs = 0, ss = 2;
    for (int kt = 0; kt < NSTEP; ++kt) {
        if (kt < NSTEP - 1) asm volatile("s_waitcnt vmcnt(6)" ::: "memory");
        else                asm volatile("s_waitcnt vmcnt(0)" ::: "memory");
        __builtin_amdgcn_s_barrier();
        asm volatile("" ::: "memory");
        if (kt < NSTEP - 2)
            stage_out(ctx, WoT, m0, n0, (kt + 2) * 32, sA[ss], sB[ss], w, t);

        const bf16* pa = sA[rs] + (w * 64 + lc) * 32 + lr * 8;
        const bf16* pb = sB[rs] + lc * 32 + lr * 8;
        bf16x8 af[4], bfr[4];
#pragma unroll
        for (int m = 0; m < 4; ++m) af[m] = *(const bf16x8*)(pa + m * 16 * 32);
#pragma unroll
        for (int n = 0; n < 4; ++n) bfr[n] = *(const bf16x8*)(pb + n * 16 * 32);
#pragma unroll
        for (int m = 0; m < 4; ++m)
#pragma unroll
            for (int n = 0; n < 4; ++n)
                acc[m][n] = mfma16(af[m], bfr[n], acc[m][n]);
        rs = (rs == 2) ? 0 : rs + 1;
        ss = (ss == 2) ? 0 : ss + 1;
    }

    int row0 = m0 + w * 64 + lr * 4;
#pragma unroll
    for (int nf = 0; nf < 4; ++nf) {
        int col = n0 + lc + nf * 16;
        float bvv = bo[col];
#pragma unroll
        for (int mf = 0; mf < 4; ++mf)
#pragma unroll
            for (int r = 0; r < 4; ++r)
                out[(size_t)(row0 + mf * 16 + r) * DIM + col] = acc[mf][nf][r] + bvv;
    }
}

// ================ flash attention: 4-wave blocks, LDS-staged shared K/V, window 256 (R11) ================
__global__ __launch_bounds__(256, 3) void attn_kernel(const bf16* __restrict__ qT, const bf16* __restrict__ kT,
                                                      const bf16* __restrict__ vT, bf16* __restrict__ ctx) {
    int bid = blockIdx.x + 16 * blockIdx.y;      // 512 blocks
    int xcd = bid & 7, idx = bid >> 3;           // XCD-bijective: 8 x 4bh x 16qb
    int bh = xcd * 4 + (idx >> 4);               // 4 heads per XCD (2MB KV < 4MB L2)
    int qb = idx & 15;
    int b = bh >> 4, h = bh & 15;
    int t = threadIdx.x, lane = t & 63, w = t >> 6;
    int lc = lane & 15, lr = lane >> 4;

    __shared__ bf16 sK[2][4096];                 // [slot][key(64)][d(64)] swizzled
    __shared__ bf16 sV[2][4096];                 // [slot][d(64)][key(64)] swizzled
    __shared__ bf16 sP[4][2048];                 // per-wave P buffer

    const bf16* Qb = qT + (size_t)bh * S_LEN * HDIM;
    const bf16* Kb = kT + (size_t)bh * S_LEN * HDIM;
    const bf16* Vb = vT + (size_t)bh * HDIM * S_LEN;

    const float SCL = 0.125f * 1.44269504089f;   // 1/sqrt(64) * log2(e)
    const int swz = (lc & 7) << 4;               // involution swizzle (bytes)
    char* sPw = (char*)sP[w];

    int q0 = qb * 128 + w * 32;
    int kt_lo_b = (qb >= 2) ? (qb * 128 - 256) >> 6 : 0;
    int kt_hi_b = (qb * 128 + 127) >> 6;
    int klo_w = (q0 >= 256) ? (q0 - 256) >> 6 : 0;
    int khi_w = (q0 + 31) >> 6;

    bf16x8 qf[2][2];
#pragma unroll
    for (int mf = 0; mf < 2; ++mf)
#pragma unroll
        for (int kk = 0; kk < 2; ++kk)
            qf[mf][kk] = *(const bf16x8*)(Qb + (size_t)(q0 + mf * 16 + lc) * HDIM + kk * 32 + lr * 8);

    f32x4 accO[2][4] = {};
    float mrun[2] = { -30000.0f, -30000.0f };
    float lrun[2] = { 0.0f, 0.0f };

#define STAGE_KV(kt_, s_) {                                                             \
        int kbase_ = (kt_) * 64;                                                        \
        _Pragma("unroll")                                                               \
        for (int p = 0; p < 2; ++p) {                                                   \
            int c = p * 256 + t;                                                        \
            int row = c >> 3, ch = c & 7;                                               \
            int colb = (ch * 16) ^ ((row & 7) << 4);                                    \
            bf16* dst = (bf16*)&sK[s_][0] + (p * 256 + (t & ~63)) * 8;                  \
            gload_lds16(Kb + (size_t)(kbase_ + row) * HDIM + (colb >> 1), dst);         \
            bf16* dsv = (bf16*)&sV[s_][0] + (p * 256 + (t & ~63)) * 8;                  \
            gload_lds16(Vb + (size_t)row * S_LEN + kbase_ + (colb >> 1), dsv);          \
        }                                                                               \
    }

    STAGE_KV(kt_lo_b, 0);
    if (kt_lo_b + 1 <= kt_hi_b) STAGE_KV(kt_lo_b + 1, 1);

    for (int kt = kt_lo_b; kt <= kt_hi_b; ++kt) {
        int s = (kt - kt_lo_b) & 1;
        if (kt < kt_hi_b) asm volatile("s_waitcnt vmcnt(4)" ::: "memory");
        else              asm volatile("s_waitcnt vmcnt(0)" ::: "memory");
        __builtin_amdgcn_s_barrier();
        asm volatile("" ::: "memory");

        if (kt >= klo_w && kt <= khi_w) {
            int kbase = kt * 64;
            const char* kb = (const char*)&sK[s][0];
            const char* vb = (const char*)&sV[s][0];

            f32x4 sacc[2][4] = {};
            __builtin_amdgcn_s_setprio(1);
#pragma unroll
            for (int nf = 0; nf < 4; ++nf) {
                int key = nf * 16 + lc;
#pragma unroll
                for (int kk = 0; kk < 2; ++kk) {
                    bf16x8 kf = *(const bf16x8*)(kb + key * 128 + ((kk * 64 + lr * 16) ^ swz));
                    sacc[0][nf] = mfma16(kf, qf[0][kk], sacc[0][nf]);
                    sacc[1][nf] = mfma16(kf, qf[1][kk], sacc[1][nf]);
                }
            }
            __builtin_amdgcn_s_setprio(0);
#pragma unroll
            for (int mf = 0; mf < 2; ++mf) {
                int qi = q0 + mf * 16 + lc;
#pragma unroll
                for (int nf = 0; nf < 4; ++nf)
#pragma unroll
                    for (int r = 0; r < 4; ++r) {
                        int ki = kbase + nf * 16 + lr * 4 + r;
                        bool keep = (ki <= qi) && (ki >= qi - 256);
                        sacc[mf][nf][r] = keep ? sacc[mf][nf][r] * SCL : -30000.0f;
                    }
            }
#pragma unroll
            for (int mf = 0; mf < 2; ++mf) {
                float mx = sacc[mf][0][0];
#pragma unroll
                for (int nf = 0; nf < 4; ++nf)
#pragma unroll
                    for (int r = 0; r < 4; ++r) mx = fmaxf(mx, sacc[mf][nf][r]);
                mx = fmaxf(mx, __shfl_xor(mx, 16));
                mx = fmaxf(mx, __shfl_xor(mx, 32));
                float mnew = fmaxf(mrun[mf], mx);
                float alpha = exp2fast(mrun[mf] - mnew);
                mrun[mf] = mnew;
                float rsum = 0.0f;
#pragma unroll
                for (int nf = 0; nf < 4; ++nf)
#pragma unroll
                    for (int r = 0; r < 4; ++r) {
                        float e = exp2fast(sacc[mf][nf][r] - mnew);
                        sacc[mf][nf][r] = e;
                        rsum += e;
                    }
                rsum += __shfl_xor(rsum, 16);
                rsum += __shfl_xor(rsum, 32);
                lrun[mf] = lrun[mf] * alpha + rsum;
                float aq[4];
#pragma unroll
                for (int r = 0; r < 4; ++r) aq[r] = __shfl(alpha, lr * 4 + r);
#pragma unroll
                for (int n4 = 0; n4 < 4; ++n4)
#pragma unroll
                    for (int r = 0; r < 4; ++r) accO[mf][n4][r] *= aq[r];
            }
#pragma unroll
            for (int mf = 0; mf < 2; ++mf)
#pragma unroll
                for (int nf = 0; nf < 4; ++nf) {
                    bf16x4 o = { (bf16)sacc[mf][nf][0], (bf16)sacc[mf][nf][1],
                                 (bf16)sacc[mf][nf][2], (bf16)sacc[mf][nf][3] };
                    int wb = ((mf * 16 + lc) * 64 + nf * 16 + lr * 4) * 2;
                    *(bf16x4*)(sPw + (wb ^ swz)) = o;
                }
            asm volatile("s_waitcnt lgkmcnt(0)" ::: "memory");
            bf16x8 pf[2][2];
#pragma unroll
            for (int mf = 0; mf < 2; ++mf)
#pragma unroll
                for (int kk = 0; kk < 2; ++kk) {
                    int rb = ((mf * 16 + lc) * 64 + kk * 32 + lr * 8) * 2;
                    pf[mf][kk] = *(const bf16x8*)(sPw + (rb ^ swz));
                }
            __builtin_amdgcn_s_setprio(1);
#pragma unroll
            for (int n4 = 0; n4 < 4; ++n4) {
                int d = n4 * 16 + lc;
#pragma unroll
                for (int kk = 0; kk < 2; ++kk) {
                    bf16x8 vf = *(const bf16x8*)(vb + d * 128 + ((kk * 64 + lr * 16) ^ swz));
                    accO[0][n4] = mfma16(pf[0][kk], vf, accO[0][n4]);
                    accO[1][n4] = mfma16(pf[1][kk], vf, accO[1][n4]);
                }
            }
            __builtin_amdgcn_s_setprio(0);
        }

        __builtin_amdgcn_s_barrier();
        asm volatile("" ::: "memory");
        if (kt + 2 <= kt_hi_b) STAGE_KV(kt + 2, s);
    }
#undef STAGE_KV

#pragma unroll
    for (int mf = 0; mf < 2; ++mf) {
        float linv = 1.0f / lrun[mf];
        float lq[4];
#pragma unroll
        for (int r = 0; r < 4; ++r) lq[r] = __shfl(linv, lr * 4 + r);
#pragma unroll
        for (int n4 = 0; n4 < 4; ++n4)
#pragma unroll
            for (int r = 0; r < 4; ++r) {
                int s = q0 + mf * 16 + lr * 4 + r;
                int d = n4 * 16 + lc;
                ctx[((size_t)(b * S_LEN + s)) * DIM + h * HDIM + d] = (bf16)(accO[mf][n4][r] * lq[r]);
            }
    }
}

extern "C" void kernel_launch(void* const* d_in, const int* in_sizes, int n_in,
                              void* d_out, int out_size, void* d_ws, size_t ws_size,
                              hipStream_t stream) {
    const float* x    = (const float*)d_in[0];
    const float* cosp = (const float*)d_in[2];
    const float* sinp = (const float*)d_in[3];
    const float* Wq   = (const float*)d_in[4];
    const float* bq   = (const float*)d_in[5];
    const float* Wk   = (const float*)d_in[6];
    const float* Wv   = (const float*)d_in[7];
    const float* bv   = (const float*)d_in[8];
    const float* Wo   = (const float*)d_in[9];
    const float* bo   = (const float*)d_in[10];
    float* out = (float*)d_out;

    char* ws = (char*)d_ws;
    const size_t MB = 1ull << 20;
    bf16* xb  = (bf16*)(ws + 0 * MB);
    bf16* WqT = (bf16*)(ws + 8 * MB);
    bf16* WkT = (bf16*)(ws + 10 * MB);
    bf16* WvT = (bf16*)(ws + 12 * MB);
    bf16* WoT = (bf16*)(ws + 14 * MB);
    bf16* qT  = (bf16*)(ws + 16 * MB);
    bf16* kT  = (bf16*)(ws + 24 * MB);
    bf16* vT  = (bf16*)(ws + 32 * MB);
    bf16* ctx = (bf16*)(ws + 40 * MB);

    cvt_x_kernel<<<4096, 256, 0, stream>>>(x, xb);
    wt_kernel<<<dim3(16, 16, 4), 256, 0, stream>>>(Wq, Wk, Wv, Wo, WqT, WkT, WvT, WoT);
    gemm_qkv_kernel<<<dim3(32, 8, 3), 256, 0, stream>>>(xb, WqT, WkT, WvT, bq, bv, cosp, sinp, qT, kT, vT);
    attn_kernel<<<dim3(16, 32), 256, 0, stream>>>(qT, kT, vT, ctx);
    gemm_out_kernel<<<dim3(32, 16), 128, 0, stream>>>(ctx, WoT, bo, out);
}